// Round 13
// baseline (60.895 us; speedup 1.0000x reference)
//
#include <hip/hip_runtime.h>

#define NUM_V 100000
#define NUM_R 1000
#define ARITY 3
#define DD 128
#define DI 192   /* D + I */
#define HH 128
#define BB 4096
#define NN 64

typedef __attribute__((ext_vector_type(4))) float f32x4;
typedef __attribute__((ext_vector_type(8))) _Float16 half8;
typedef __attribute__((ext_vector_type(2))) _Float16 half2v;

// ---------------- Fused GEMM + prep ------------------------------------------
// One kernel produces everything gather needs (R12 structure, best 60.2us):
//   VWh = f16(V @ WV + bV)   -- MFMA path
//   RWh = f16(R @ WR + bR)   -- 2 rows/block, blocks 0..499, after epilogue
//   peProd[h] = prod_a (P[a]@WP+bP)[h]  -- block 511, after epilogue
// ROUND-13 single-variable change: R12's VGPR_Count=36 proved the compiler
// SANK the A prefetch to just-in-time (a held 3-deep pipeline needs ~80 regs;
// R0's sched_barrier-pinned kernel showed VGPR=64) -- so "pipeline depth"
// was never actually tested in R6/R7/R10. Here the 2-deep pipeline is
// ENFORCED with sched_barrier(0) fences after each load-issue point (loads
// cannot cross; WAR dep on va[cur] keeps them after the consuming cvt).
// 2-deep (not 3) keeps VGPR <= 73 so 2 blocks/CU (26 waves) stay resident:
// __launch_bounds__(832, 7) pins the cap at 512/7 = 73.
__global__ __launch_bounds__(832, 7) void gemm_fused(
    const float* __restrict__ A, const float* __restrict__ WV, const float* __restrict__ bV,
    const float* __restrict__ R, const float* __restrict__ WR, const float* __restrict__ bR,
    const float* __restrict__ P, const float* __restrict__ WP, const float* __restrict__ bP,
    _Float16* __restrict__ VWh, _Float16* __restrict__ RWh, float* __restrict__ peProd,
    int M) {
    __shared__ unsigned short bsm[24576];  // 48 KB f16 B-table, wfrag layout

    const int tid = threadIdx.x;
    const int l = tid & 63;
    const int wv = tid >> 6;  // 0..12
    const int bid = blockIdx.x;

    const int tile = wv * 512 + bid;  // 0..6655, each hit exactly once
    const int rowbase = tile * 16;
    const bool active = rowbase < M;  // wave-uniform (M = 6250*16 exactly)

    // bias per col-tile
    float bcol[8];
#pragma unroll
    for (int ct = 0; ct < 8; ++ct) bcol[ct] = bV[ct * 16 + (l & 15)];

    // A fragment pointer: row = rowbase + (l&15), k-base (l>>4)*8
    const float* aptr;
    {
        int rr = rowbase + (l & 15);
        if (rr >= M) rr = M - 1;
        aptr = A + (size_t)rr * DI + (l >> 4) * 8;
    }

    f32x4 acc[8];
#pragma unroll
    for (int ct = 0; ct < 8; ++ct) acc[ct] = (f32x4){0.f, 0.f, 0.f, 0.f};

    float4 va[2][2];  // [buf][half] -- 2-deep HELD pipeline (enforced below)
#define LOAD_A(buf, ks)                                      \
    do {                                                     \
        va[buf][0] = *(const float4*)(aptr + (ks) * 32);     \
        va[buf][1] = *(const float4*)(aptr + (ks) * 32 + 4); \
    } while (0)

    // prologue A loads first (start HBM traffic at t=0); fence so the
    // compiler cannot sink them into the loop
    if (active) {
        LOAD_A(0, 0);
        LOAD_A(1, 1);
    }
    __builtin_amdgcn_sched_barrier(0);

    // ---- build f16 B-table in LDS from WV (L2-hot; overlaps A latency) ----
    // ushort idx = (ks*8+ct)*512 + lane*8 + j  holds f16(WV[k][col]) with
    // k = ks*32+(lane>>4)*8+j, col = ct*16+(lane&15)  (== wfrag layout).
    if (tid < 768) {
#pragma unroll
        for (int i = 0; i < 4; ++i) {
            const int g = i * 768 + tid;          // group 0..3071 (8 ushorts each)
            const int ks = g >> 9;                // 0..5
            const int ct = (g >> 6) & 7;          // 0..7
            const int ln = g & 63;                // fragment lane
            const int col = ct * 16 + (ln & 15);
            const int kbase = ks * 32 + ((ln >> 4) << 3);
            half8 hv;
#pragma unroll
            for (int j = 0; j < 8; ++j)
                hv[j] = (_Float16)WV[(size_t)(kbase + j) * HH + col];
            *(half8*)&bsm[(size_t)g * 8] = hv;
        }
    }

    __syncthreads();  // the ONLY barrier: publishes the LDS B-table

    if (active) {
#pragma unroll
        for (int ks = 0; ks < 6; ++ks) {
            const int cur = ks & 1;

            // fp32 -> f16 convert of current A fragment (8 v_cvt, RNE).
            // Compiler-counted wait here is vmcnt(2): L(ks+1) stays in flight.
            half8 ah;
            {
                half8 t;
                t[0] = (_Float16)va[cur][0].x;
                t[1] = (_Float16)va[cur][0].y;
                t[2] = (_Float16)va[cur][0].z;
                t[3] = (_Float16)va[cur][0].w;
                t[4] = (_Float16)va[cur][1].x;
                t[5] = (_Float16)va[cur][1].y;
                t[6] = (_Float16)va[cur][1].z;
                t[7] = (_Float16)va[cur][1].w;
                ah = t;
            }

            // refill this buffer for step ks+2, then fence: the load is
            // pinned BEFORE the MFMA cluster (cannot sink past the barrier),
            // giving a held 2-deep pipeline (4 loads outstanding steady).
            if (ks < 4) {
                LOAD_A(cur, ks + 2);
                __builtin_amdgcn_sched_barrier(0);
            }

#pragma unroll
            for (int ct = 0; ct < 8; ++ct) {
                const int fb = (ks * 8 + ct) * 512;  // ushort index of fragment
                half8 bh = *(const half8*)&bsm[fb + l * 8];
                acc[ct] = __builtin_amdgcn_mfma_f32_16x16x32_f16(ah, bh, acc[ct], 0, 0, 0);
            }
        }

        // epilogue: wave writes full 256B C-lines (col = ct*16 + (l&15))
        const int rb = rowbase + (l >> 4) * 4;
#pragma unroll
        for (int j = 0; j < 4; ++j) {
            const int row = rb + j;
            if (row < M) {
#pragma unroll
                for (int ct = 0; ct < 8; ++ct)
                    VWh[(size_t)row * HH + ct * 16 + (l & 15)] = (_Float16)(acc[ct][j] + bcol[ct]);
            }
        }
    }
#undef LOAD_A

    // ---- fused prep work (fills the block drain-tail; no barrier needed) ----
    if (bid < 500) {
        // proj: RWh rows bid*2, bid*2+1 (500*2 = 1000 = NUM_R exactly)
        if (tid < 256) {
            const int row = bid * 2 + (tid >> 7);
            const int col = tid & 127;
            float a2 = bR[col];
            const float* Rr = R + (size_t)row * DD;
            for (int d = 0; d < DD; ++d) a2 += Rr[d] * WR[(size_t)d * HH + col];
            RWh[(size_t)row * HH + col] = (_Float16)a2;
        }
    } else if (bid == 511) {
        // pe: peProd[h] = prod_a (P[a]@WP + bP)[h]
        if (tid < HH) {
            const int h = tid;
            float prod = 1.0f;
            for (int a = 0; a < ARITY; ++a) {
                float a2 = bP[h];
                for (int d = 0; d < DD; ++d) a2 += P[a * DD + d] * WP[d * HH + h];
                prod *= a2;
            }
            peProd[h] = prod;
        }
    }
}

// ---------------- Gather - product - neighbor-sum (fp16 tables) --------------
// out[b,h] = peProd[h] * sum_n RWh[r[b,n]][h] * prod_a VWh[e[a,b,n]][h]
__global__ __launch_bounds__(256) void gather_kernel(const int* __restrict__ r,
                                                     const int* __restrict__ e,
                                                     const _Float16* __restrict__ VWh,
                                                     const _Float16* __restrict__ RWh,
                                                     const float* __restrict__ peProd,
                                                     float* __restrict__ out) {
    __shared__ int rIdx[NN];
    __shared__ int eIdx[ARITY][NN];
    __shared__ float4 partial[3][16][2];

    const int b = blockIdx.x;
    const int tid = threadIdx.x;

    if (tid < NN) {
        rIdx[tid] = r[b * NN + tid];
    } else {
        int t = tid - NN;
        eIdx[t >> 6][t & 63] = e[(size_t)(t >> 6) * BB * NN + b * NN + (t & 63)];
    }
    __syncthreads();

    const int lane = tid & 63;
    const int wv = tid >> 6;    // 0..3
    const int q = lane >> 4;    // neighbor sub-slot 0..3
    const int ho = lane & 15;   // h-octet: h = ho*8 .. +8

    float acc8[8];
#pragma unroll
    for (int k = 0; k < 8; ++k) acc8[k] = 0.f;

#pragma unroll
    for (int it = 0; it < 4; ++it) {
        int n = it * 16 + wv * 4 + q;
        half8 rw = *(const half8*)(RWh + (size_t)rIdx[n] * HH + ho * 8);
        half8 v0 = *(const half8*)(VWh + (size_t)eIdx[0][n] * HH + ho * 8);
        half8 v1 = *(const half8*)(VWh + (size_t)eIdx[1][n] * HH + ho * 8);
        half8 v2 = *(const half8*)(VWh + (size_t)eIdx[2][n] * HH + ho * 8);
        half8 p = rw * v0;
        p = p * v1;
        p = p * v2;
#pragma unroll
        for (int k = 0; k < 8; ++k) acc8[k] += (float)p[k];
    }

    // combine the 4 neighbor sub-slots (lane quarters share ho)
#pragma unroll
    for (int k = 0; k < 8; ++k) {
        acc8[k] += __shfl_xor(acc8[k], 16);
        acc8[k] += __shfl_xor(acc8[k], 32);
    }

    if (wv > 0 && lane < 16) {
        partial[wv - 1][ho][0] = make_float4(acc8[0], acc8[1], acc8[2], acc8[3]);
        partial[wv - 1][ho][1] = make_float4(acc8[4], acc8[5], acc8[6], acc8[7]);
    }
    __syncthreads();
    if (wv == 0 && lane < 16) {
        float4 s0 = make_float4(acc8[0], acc8[1], acc8[2], acc8[3]);
        float4 s1 = make_float4(acc8[4], acc8[5], acc8[6], acc8[7]);
#pragma unroll
        for (int g = 0; g < 3; ++g) {
            float4 t0 = partial[g][ho][0], t1 = partial[g][ho][1];
            s0.x += t0.x; s0.y += t0.y; s0.z += t0.z; s0.w += t0.w;
            s1.x += t1.x; s1.y += t1.y; s1.z += t1.z; s1.w += t1.w;
        }
        float4 p0 = ((const float4*)peProd)[ho * 2];
        float4 p1 = ((const float4*)peProd)[ho * 2 + 1];
        ((float4*)(out + (size_t)b * HH))[ho * 2] =
            make_float4(s0.x * p0.x, s0.y * p0.y, s0.z * p0.z, s0.w * p0.w);
        ((float4*)(out + (size_t)b * HH))[ho * 2 + 1] =
            make_float4(s1.x * p1.x, s1.y * p1.y, s1.z * p1.z, s1.w * p1.w);
    }
}

// ---------------- Launch -----------------------------------------------------
extern "C" void kernel_launch(void* const* d_in, const int* in_sizes, int n_in,
                              void* d_out, int out_size, void* d_ws, size_t ws_size,
                              hipStream_t stream) {
    const int* r = (const int*)d_in[0];
    const int* e = (const int*)d_in[1];
    const float* V = (const float*)d_in[2];
    const float* R = (const float*)d_in[3];
    const float* P = (const float*)d_in[4];
    const float* WV = (const float*)d_in[5];
    const float* bV = (const float*)d_in[6];
    const float* WR = (const float*)d_in[7];
    const float* bR = (const float*)d_in[8];
    const float* WP = (const float*)d_in[9];
    const float* bP = (const float*)d_in[10];
    float* out = (float*)d_out;

    // ws layout: VWh [NUM_V,H] fp16 | RWh [NUM_R,H] fp16 | peProd [H] f32
    _Float16* VWh = (_Float16*)d_ws;
    _Float16* RWh = VWh + (size_t)NUM_V * HH;
    float* peProd = (float*)(RWh + (size_t)NUM_R * HH);

    gemm_fused<<<512, 832, 0, stream>>>(V, WV, bV, R, WR, bR, P, WP, bP,
                                        VWh, RWh, peProd, NUM_V);
    gather_kernel<<<BB, 256, 0, stream>>>(r, e, VWh, RWh, peProd, out);
}

// Round 14
// 57.330 us; speedup vs baseline: 1.0622x; 1.0622x over previous
//
#include <hip/hip_runtime.h>

#define NUM_V 100000
#define NUM_R 1000
#define ARITY 3
#define DD 128
#define DI 192   /* D + I */
#define HH 128
#define BB 4096
#define NN 64

typedef __attribute__((ext_vector_type(4))) float f32x4;
typedef __attribute__((ext_vector_type(8))) _Float16 half8;
typedef __attribute__((ext_vector_type(2))) _Float16 half2v;

// ---------------- Fused GEMM + prep, full-tile register burst ----------------
// R14 wall test: each wave issues ALL 12 A-loads (12 KB -> 48 VGPRs) in one
// up-front burst, overlapped with the in-LDS B-table build; __syncthreads'
// vmcnt(0) drain lands after both. The K-loop then has ZERO memory waits.
// One memory round-trip per tile (vs 6 dependent steps in R10-R13) at
// 16 waves/CU (vs R9's burst at 6 w/CU). 512-thread blocks (8 waves),
// __launch_bounds__(512,4) -> VGPR cap 128, 2 blocks/CU resident.
// tile = bid*8+wv: each block reads one contiguous 96 KB A-region.
// Prior facts honored: acc in AGPRs (VGPR_Count excludes them); loads cannot
// sink past __syncthreads (full fence); nt-stores regress (R11); prep fusion
// worth ~8.5us (R12).
__global__ __launch_bounds__(512, 4) void gemm_fused(
    const float* __restrict__ A, const float* __restrict__ WV, const float* __restrict__ bV,
    const float* __restrict__ R, const float* __restrict__ WR, const float* __restrict__ bR,
    const float* __restrict__ P, const float* __restrict__ WP, const float* __restrict__ bP,
    _Float16* __restrict__ VWh, _Float16* __restrict__ RWh, float* __restrict__ peProd,
    int M) {
    __shared__ unsigned short bsm[24576];  // 48 KB f16 B-table, wfrag layout

    const int tid = threadIdx.x;
    const int l = tid & 63;
    const int wv = tid >> 6;  // 0..7
    const int bid = blockIdx.x;

    const int tile = bid * 8 + wv;    // contiguous per block: 96 KB A-region
    const int rowbase = tile * 16;
    const bool active = rowbase < M;  // wave-uniform (6250*16 = M exactly)

    // A fragment pointer: row = rowbase + (l&15), k-base (l>>4)*8 (clamped)
    const float* aptr;
    {
        int rr = rowbase + (l & 15);
        if (rr >= M) rr = M - 1;
        aptr = A + (size_t)rr * DI + (l >> 4) * 8;
    }

    // ---- FULL-TILE BURST: 12 x global_load_dwordx4 (48 VGPRs), issued
    // back-to-back at t=0, unconditional (clamped), pinned before the build.
    f32x4 va[6][2];
#pragma unroll
    for (int ks = 0; ks < 6; ++ks) {
        va[ks][0] = *(const f32x4*)(aptr + ks * 32);
        va[ks][1] = *(const f32x4*)(aptr + ks * 32 + 4);
    }
    __builtin_amdgcn_sched_barrier(0);

    // bias per col-tile
    float bcol[8];
#pragma unroll
    for (int ct = 0; ct < 8; ++ct) bcol[ct] = bV[ct * 16 + (l & 15)];

    // ---- build f16 B-table in LDS from WV (L2-hot; overlaps burst latency)
    // ushort idx = (ks*8+ct)*512 + lane*8 + j  holds f16(WV[k][col]) with
    // k = ks*32+(lane>>4)*8+j, col = ct*16+(lane&15)  (wfrag layout).
#pragma unroll
    for (int i = 0; i < 6; ++i) {
        const int g = i * 512 + tid;          // group 0..3071 (8 ushorts each)
        const int ks = g >> 9;                // 0..5
        const int ct = (g >> 6) & 7;          // 0..7
        const int ln = g & 63;                // fragment lane
        const int col = ct * 16 + (ln & 15);
        const int kbase = ks * 32 + ((ln >> 4) << 3);
        half8 hv;
#pragma unroll
        for (int j = 0; j < 8; ++j)
            hv[j] = (_Float16)WV[(size_t)(kbase + j) * HH + col];
        *(half8*)&bsm[(size_t)g * 8] = hv;
    }

    __syncthreads();  // publishes B-table; vmcnt(0) drain retires the A-burst

    if (active) {
        f32x4 acc[8];
#pragma unroll
        for (int ct = 0; ct < 8; ++ct) acc[ct] = (f32x4){0.f, 0.f, 0.f, 0.f};

        // ---- K-loop: ZERO memory waits (A in registers, B in LDS)
#pragma unroll
        for (int ks = 0; ks < 6; ++ks) {
            half8 ah;
            {
                half8 t;
                t[0] = (_Float16)va[ks][0].x;
                t[1] = (_Float16)va[ks][0].y;
                t[2] = (_Float16)va[ks][0].z;
                t[3] = (_Float16)va[ks][0].w;
                t[4] = (_Float16)va[ks][1].x;
                t[5] = (_Float16)va[ks][1].y;
                t[6] = (_Float16)va[ks][1].z;
                t[7] = (_Float16)va[ks][1].w;
                ah = t;
            }
#pragma unroll
            for (int ct = 0; ct < 8; ++ct) {
                const int fb = (ks * 8 + ct) * 512;  // ushort index of fragment
                half8 bh = *(const half8*)&bsm[fb + l * 8];
                acc[ct] = __builtin_amdgcn_mfma_f32_16x16x32_f16(ah, bh, acc[ct], 0, 0, 0);
            }
        }

        // epilogue: wave writes full 256B C-lines (col = ct*16 + (l&15))
        const int rb = rowbase + (l >> 4) * 4;
#pragma unroll
        for (int j = 0; j < 4; ++j) {
            const int row = rb + j;
            if (row < M) {
#pragma unroll
                for (int ct = 0; ct < 8; ++ct)
                    VWh[(size_t)row * HH + ct * 16 + (l & 15)] = (_Float16)(acc[ct][j] + bcol[ct]);
            }
        }
    }

    // ---- fused prep work (fills the block drain-tail; no barrier needed) ----
    if (bid < 500) {
        // proj: RWh rows bid*2, bid*2+1 (500*2 = 1000 = NUM_R exactly)
        if (tid < 256) {
            const int row = bid * 2 + (tid >> 7);
            const int col = tid & 127;
            float a2 = bR[col];
            const float* Rr = R + (size_t)row * DD;
            for (int d = 0; d < DD; ++d) a2 += Rr[d] * WR[(size_t)d * HH + col];
            RWh[(size_t)row * HH + col] = (_Float16)a2;
        }
    } else if (bid == 501) {
        // pe: peProd[h] = prod_a (P[a]@WP + bP)[h]
        if (tid < HH) {
            const int h = tid;
            float prod = 1.0f;
            for (int a = 0; a < ARITY; ++a) {
                float a2 = bP[h];
                for (int d = 0; d < DD; ++d) a2 += P[a * DD + d] * WP[d * HH + h];
                prod *= a2;
            }
            peProd[h] = prod;
        }
    }
}

// ---------------- Gather - product - neighbor-sum (fp16 tables) --------------
// out[b,h] = peProd[h] * sum_n RWh[r[b,n]][h] * prod_a VWh[e[a,b,n]][h]
__global__ __launch_bounds__(256) void gather_kernel(const int* __restrict__ r,
                                                     const int* __restrict__ e,
                                                     const _Float16* __restrict__ VWh,
                                                     const _Float16* __restrict__ RWh,
                                                     const float* __restrict__ peProd,
                                                     float* __restrict__ out) {
    __shared__ int rIdx[NN];
    __shared__ int eIdx[ARITY][NN];
    __shared__ float4 partial[3][16][2];

    const int b = blockIdx.x;
    const int tid = threadIdx.x;

    if (tid < NN) {
        rIdx[tid] = r[b * NN + tid];
    } else {
        int t = tid - NN;
        eIdx[t >> 6][t & 63] = e[(size_t)(t >> 6) * BB * NN + b * NN + (t & 63)];
    }
    __syncthreads();

    const int lane = tid & 63;
    const int wv = tid >> 6;    // 0..3
    const int q = lane >> 4;    // neighbor sub-slot 0..3
    const int ho = lane & 15;   // h-octet: h = ho*8 .. +8

    float acc8[8];
#pragma unroll
    for (int k = 0; k < 8; ++k) acc8[k] = 0.f;

#pragma unroll
    for (int it = 0; it < 4; ++it) {
        int n = it * 16 + wv * 4 + q;
        half8 rw = *(const half8*)(RWh + (size_t)rIdx[n] * HH + ho * 8);
        half8 v0 = *(const half8*)(VWh + (size_t)eIdx[0][n] * HH + ho * 8);
        half8 v1 = *(const half8*)(VWh + (size_t)eIdx[1][n] * HH + ho * 8);
        half8 v2 = *(const half8*)(VWh + (size_t)eIdx[2][n] * HH + ho * 8);
        half8 p = rw * v0;
        p = p * v1;
        p = p * v2;
#pragma unroll
        for (int k = 0; k < 8; ++k) acc8[k] += (float)p[k];
    }

    // combine the 4 neighbor sub-slots (lane quarters share ho)
#pragma unroll
    for (int k = 0; k < 8; ++k) {
        acc8[k] += __shfl_xor(acc8[k], 16);
        acc8[k] += __shfl_xor(acc8[k], 32);
    }

    if (wv > 0 && lane < 16) {
        partial[wv - 1][ho][0] = make_float4(acc8[0], acc8[1], acc8[2], acc8[3]);
        partial[wv - 1][ho][1] = make_float4(acc8[4], acc8[5], acc8[6], acc8[7]);
    }
    __syncthreads();
    if (wv == 0 && lane < 16) {
        float4 s0 = make_float4(acc8[0], acc8[1], acc8[2], acc8[3]);
        float4 s1 = make_float4(acc8[4], acc8[5], acc8[6], acc8[7]);
#pragma unroll
        for (int g = 0; g < 3; ++g) {
            float4 t0 = partial[g][ho][0], t1 = partial[g][ho][1];
            s0.x += t0.x; s0.y += t0.y; s0.z += t0.z; s0.w += t0.w;
            s1.x += t1.x; s1.y += t1.y; s1.z += t1.z; s1.w += t1.w;
        }
        float4 p0 = ((const float4*)peProd)[ho * 2];
        float4 p1 = ((const float4*)peProd)[ho * 2 + 1];
        ((float4*)(out + (size_t)b * HH))[ho * 2] =
            make_float4(s0.x * p0.x, s0.y * p0.y, s0.z * p0.z, s0.w * p0.w);
        ((float4*)(out + (size_t)b * HH))[ho * 2 + 1] =
            make_float4(s1.x * p1.x, s1.y * p1.y, s1.z * p1.z, s1.w * p1.w);
    }
}

// ---------------- Launch -----------------------------------------------------
extern "C" void kernel_launch(void* const* d_in, const int* in_sizes, int n_in,
                              void* d_out, int out_size, void* d_ws, size_t ws_size,
                              hipStream_t stream) {
    const int* r = (const int*)d_in[0];
    const int* e = (const int*)d_in[1];
    const float* V = (const float*)d_in[2];
    const float* R = (const float*)d_in[3];
    const float* P = (const float*)d_in[4];
    const float* WV = (const float*)d_in[5];
    const float* bV = (const float*)d_in[6];
    const float* WR = (const float*)d_in[7];
    const float* bR = (const float*)d_in[8];
    const float* WP = (const float*)d_in[9];
    const float* bP = (const float*)d_in[10];
    float* out = (float*)d_out;

    // ws layout: VWh [NUM_V,H] fp16 | RWh [NUM_R,H] fp16 | peProd [H] f32
    _Float16* VWh = (_Float16*)d_ws;
    _Float16* RWh = VWh + (size_t)NUM_V * HH;
    float* peProd = (float*)(RWh + (size_t)NUM_R * HH);

    const int tiles = (NUM_V + 15) / 16;            // 6250
    gemm_fused<<<(tiles + 7) / 8, 512, 0, stream>>>(V, WV, bV, R, WR, bR, P, WP, bP,
                                                    VWh, RWh, peProd, NUM_V);
    gather_kernel<<<BB, 256, 0, stream>>>(r, e, VWh, RWh, peProd, out);
}